// Round 4
// baseline (551.888 us; speedup 1.0000x reference)
//
#include <hip/hip_runtime.h>
#include <hip/hip_bf16.h>

// Problem dims (StandardAttention): x[4,96,256,256], heads=3
#define B_  4
#define C_  96
#define H_  256
#define W_  256
#define N_  (H_*W_)      // 65536
#define C3_ 288
#define HEAD_ 3
#define HC_ 32
#define EPS_ 1e-12f
#define XP_ 104          // padded LDS row stride (ushorts): 52 words -> 2 lanes/bank (free)
#define SPLITS_ 32       // one split per 8-row band (fused dw+QK^T)

typedef __attribute__((ext_vector_type(8))) short short8;
typedef __attribute__((ext_vector_type(4))) float f32x4;

// ---- bf16 helpers (raw ushort storage) -------------------------------------
__device__ __forceinline__ unsigned short f2bf(float f) {
  unsigned u = __float_as_uint(f);
  u += 0x7fffu + ((u >> 16) & 1u);      // round-to-nearest-even
  return (unsigned short)(u >> 16);
}
__device__ __forceinline__ float bf2f(unsigned short h) {
  return __uint_as_float((unsigned)h << 16);
}
__device__ __forceinline__ float bf_lo(unsigned u) { return __uint_as_float(u << 16); }
__device__ __forceinline__ float bf_hi(unsigned u) { return __uint_as_float(u & 0xffff0000u); }
__device__ __forceinline__ unsigned pack_bf(float a, float b) {
  return (unsigned)f2bf(a) | ((unsigned)f2bf(b) << 16);
}
__device__ __forceinline__ unsigned cvt_pk(float lo, float hi) {
  unsigned r;
  asm("v_cvt_pk_bf16_f32 %0, %1, %2" : "=v"(r) : "v"(lo), "v"(hi));
  return r;
}

// ---------------- K1: qkv = qkv_w @ x + qkv_b via MFMA ----------------------
// Round-1 proven form (85.6 us measured): 512 thr = 8 waves x 16 px; W staged
// once in LDS (padded rows, fp32->bf16 on the fly); B-frags from global.
__global__ __launch_bounds__(512) void k1_mfma(
    const float* __restrict__ x, const float* __restrict__ wsrc,
    const float* __restrict__ bias, unsigned short* __restrict__ out) {
  __shared__ unsigned short Wl[C3_ * XP_];    // 59904 B
  __shared__ float Bl[C3_];
  const int tid = threadIdx.x;
  const int b = blockIdx.y;
  for (int i = tid; i < C3_ * C_; i += 512)
    Wl[(i / 96) * XP_ + (i % 96)] = f2bf(wsrc[i]);
  for (int i = tid; i < C3_; i += 512) Bl[i] = bias[i];
  __syncthreads();
  const int lane = tid & 63;
  const int wv = tid >> 6;                    // 0..7
  const int l15 = lane & 15, quad = lane >> 4;
  const int gpix = blockIdx.x * 128 + wv * 16 + l15;
  const float* xcol = x + (size_t)b * C_ * N_ + gpix;
  short8 bfr[3];
#pragma unroll
  for (int kc = 0; kc < 3; ++kc) {
#pragma unroll
    for (int u = 0; u < 8; ++u)
      bfr[kc][u] = (short)f2bf(xcol[(size_t)(kc * 32 + quad * 8 + u) * N_]);
  }
  f32x4 acc[18];
#pragma unroll
  for (int m = 0; m < 18; ++m) acc[m] = (f32x4){0.f, 0.f, 0.f, 0.f};
#pragma unroll
  for (int m = 0; m < 18; ++m) {
#pragma unroll
    for (int kc = 0; kc < 3; ++kc) {
      const short8 afr = *reinterpret_cast<const short8*>(
          &Wl[(m * 16 + l15) * XP_ + kc * 32 + quad * 8]);
      acc[m] = __builtin_amdgcn_mfma_f32_16x16x32_bf16(afr, bfr[kc], acc[m], 0, 0, 0);
    }
  }
  unsigned short* ob = out + (size_t)b * C3_ * N_ + gpix;
#pragma unroll
  for (int m = 0; m < 18; ++m) {
    const int chb = m * 16 + quad * 4;
#pragma unroll
    for (int r = 0; r < 4; ++r)
      ob[(size_t)(chb + r) * N_] = f2bf(acc[m][r] + Bl[chb + r]);
  }
}

// ---------------- helpers for fused dw ------------------------------------
__device__ __forceinline__ void load10v(const unsigned short* p, int y, int x0,
                                        float* d) {
  if ((unsigned)y >= 256u) {
#pragma unroll
    for (int j = 0; j < 10; ++j) d[j] = 0.f;
    return;
  }
  const unsigned short* rp = p + (size_t)y * W_;
  const uint4 u = *reinterpret_cast<const uint4*>(rp + x0);
  d[1] = bf_lo(u.x); d[2] = bf_hi(u.x); d[3] = bf_lo(u.y); d[4] = bf_hi(u.y);
  d[5] = bf_lo(u.z); d[6] = bf_hi(u.z); d[7] = bf_lo(u.w); d[8] = bf_hi(u.w);
  d[0] = (x0 > 0)   ? bf2f(rp[x0 - 1]) : 0.f;
  d[9] = (x0 < 248) ? bf2f(rp[x0 + 8]) : 0.f;
}

// 3x3 depthwise for 8 px of one row of one channel; returns bf16 frag,
// accumulates sum of squares for the l2-norm.
__device__ __forceinline__ short8 dw8(const unsigned short* p, int y, int x0,
                                      const float* t, float& ss) {
  float a[10], c[10], d[10];
  load10v(p, y - 1, x0, a);
  load10v(p, y,     x0, c);
  load10v(p, y + 1, x0, d);
  float o[8];
#pragma unroll
  for (int j = 0; j < 8; ++j) {
    o[j] = t[9] + t[0] * a[j] + t[1] * a[j + 1] + t[2] * a[j + 2]
                + t[3] * c[j] + t[4] * c[j + 1] + t[5] * c[j + 2]
                + t[6] * d[j] + t[7] * d[j + 1] + t[8] * d[j + 2];
    ss += o[j] * o[j];
  }
  union { short8 s; unsigned u[4]; } r;
  r.u[0] = cvt_pk(o[0], o[1]); r.u[1] = cvt_pk(o[2], o[3]);
  r.u[2] = cvt_pk(o[4], o[5]); r.u[3] = cvt_pk(o[6], o[7]);
  return r.s;
}

// ---------------- K2a: FUSED dw(Q,K) + QK^T partial + norm partials --------
// Grid (32 bands, 3 heads, 4 b) x 512 thr. Wave w = 32-px window; lane
// (l15,quad) = (channel-within-16, 8-px strip). dw outputs ARE the MFMA
// fragments (k-dim = pixels): zero cross-lane traffic. dw-Q/dw-K are never
// written to global (saves 200 MB vs separate dw + attn kernels).
__global__ __launch_bounds__(512) void k_dwqk(
    const unsigned short* __restrict__ A, const float* __restrict__ w9,
    const float* __restrict__ bias, float* __restrict__ part,
    float* __restrict__ ssbuf) {
  __shared__ float taps[64][10];      // [0..31]=Q-ch, [32..63]=K-ch; [9]=bias
  __shared__ float redbuf[8][1024];   // 32 KB wave partial reduce
  const int band = blockIdx.x, h = blockIdx.y, b = blockIdx.z;
  const int tid = threadIdx.x;
  for (int i = tid; i < 640; i += 512) {
    const int cl = i / 10, k = i % 10;
    const int ach = (cl < 32) ? (h * HC_ + cl) : (C_ + h * HC_ + (cl - 32));
    taps[cl][k] = (k < 9) ? w9[ach * 9 + k] : bias[ach];
  }
  __syncthreads();
  const int wv = tid >> 6;            // px window 0..7
  const int lane = tid & 63;
  const int l15 = lane & 15, quad = lane >> 4;
  const int x0 = wv * 32 + quad * 8;  // x within row
  const int y0 = band * 8;
  const unsigned short* pQ0 = A + ((size_t)(b * C3_ + h * HC_ + l15)) * N_;
  const unsigned short* pQ1 = pQ0 + (size_t)16 * N_;
  const unsigned short* pK0 = A + ((size_t)(b * C3_ + C_ + h * HC_ + l15)) * N_;
  const unsigned short* pK1 = pK0 + (size_t)16 * N_;
  float ss0 = 0.f, ss1 = 0.f, ss2 = 0.f, ss3 = 0.f;
  f32x4 acc[2][2];
#pragma unroll
  for (int qi = 0; qi < 2; ++qi)
#pragma unroll
    for (int kj = 0; kj < 2; ++kj) acc[qi][kj] = (f32x4){0.f, 0.f, 0.f, 0.f};
  for (int y = y0; y < y0 + 8; ++y) {
    const short8 fq0 = dw8(pQ0, y, x0, &taps[l15][0],      ss0);
    const short8 fq1 = dw8(pQ1, y, x0, &taps[l15 + 16][0], ss1);
    const short8 fk0 = dw8(pK0, y, x0, &taps[32 + l15][0], ss2);
    const short8 fk1 = dw8(pK1, y, x0, &taps[48 + l15][0], ss3);
    acc[0][0] = __builtin_amdgcn_mfma_f32_16x16x32_bf16(fq0, fk0, acc[0][0], 0, 0, 0);
    acc[0][1] = __builtin_amdgcn_mfma_f32_16x16x32_bf16(fq0, fk1, acc[0][1], 0, 0, 0);
    acc[1][0] = __builtin_amdgcn_mfma_f32_16x16x32_bf16(fq1, fk0, acc[1][0], 0, 0, 0);
    acc[1][1] = __builtin_amdgcn_mfma_f32_16x16x32_bf16(fq1, fk1, acc[1][1], 0, 0, 0);
  }
  // norms: each lane's strip contributes once per channel
  atomicAdd(&ssbuf[b * 192 + h * HC_ + l15],            ss0);
  atomicAdd(&ssbuf[b * 192 + h * HC_ + l15 + 16],       ss1);
  atomicAdd(&ssbuf[b * 192 + 96 + h * HC_ + l15],       ss2);
  atomicAdd(&ssbuf[b * 192 + 96 + h * HC_ + l15 + 16],  ss3);
  // cross-wave reduce of the 32x32 tile (D: row = q-ch quad*4+r(+16qi), col = k-ch l15(+16kj))
#pragma unroll
  for (int qi = 0; qi < 2; ++qi)
#pragma unroll
    for (int kj = 0; kj < 2; ++kj)
#pragma unroll
      for (int r = 0; r < 4; ++r)
        redbuf[wv][(qi * 16 + quad * 4 + r) * 32 + kj * 16 + l15] = acc[qi][kj][r];
  __syncthreads();
  float* pp = part + (size_t)band * (B_ * HEAD_ * 1024) + ((size_t)(b * HEAD_ + h)) * 1024;
  for (int e = tid; e < 1024; e += 512) {
    float s = 0.f;
#pragma unroll
    for (int w = 0; w < 8; ++w) s += redbuf[w][e];
    pp[e] = s;
  }
}

// ---------------- K2b: dw conv for V only, in-place (proven k_dw_reg) -------
__global__ __launch_bounds__(256) void k_dwv(
    unsigned short* a, const float* __restrict__ w9,
    const float* __restrict__ bias) {
  const int bc = blockIdx.x;            // 0..383
  const int b = bc / 96, cv = bc % 96;
  const int ch = 2 * C_ + cv;
  unsigned short* p = a + ((size_t)(b * C3_ + ch)) * N_;
  const int tid = threadIdx.x;
  const int tr = tid >> 5;              // 0..7 row segment
  const int tc = tid & 31;
  const int x0 = tc * 8;
  const int y0 = tr * 32;
  float wv[9];
#pragma unroll
  for (int i = 0; i < 9; ++i) wv[i] = w9[ch * 9 + i];
  const float bv = bias[ch];

  auto load_row = [&](int y, float* d) {
    if ((unsigned)y >= 256u) {
#pragma unroll
      for (int j = 0; j < 10; ++j) d[j] = 0.f;
      return;
    }
    const unsigned short* rp = p + (size_t)y * W_;
    const uint4 u = *reinterpret_cast<const uint4*>(rp + x0);
    d[1] = bf_lo(u.x); d[2] = bf_hi(u.x); d[3] = bf_lo(u.y); d[4] = bf_hi(u.y);
    d[5] = bf_lo(u.z); d[6] = bf_hi(u.z); d[7] = bf_lo(u.w); d[8] = bf_hi(u.w);
    d[0] = (tc > 0) ? bf2f(rp[x0 - 1]) : 0.f;
    d[9] = (tc < 31) ? bf2f(rp[x0 + 8]) : 0.f;
  };

  float rm[10], rc[10], rn[10], rb[10];
  load_row(y0 - 1, rm);
  load_row(y0, rc);
  load_row(y0 + 1, rn);
  load_row(y0 + 32, rb);     // bottom boundary: original data, pre-barrier
  __syncthreads();           // all preloads done before any write

  for (int y = y0; y < y0 + 32; ++y) {
    float o[8];
#pragma unroll
    for (int j = 0; j < 8; ++j) {
      o[j] = bv + wv[0] * rm[j] + wv[1] * rm[j + 1] + wv[2] * rm[j + 2]
                + wv[3] * rc[j] + wv[4] * rc[j + 1] + wv[5] * rc[j + 2]
                + wv[6] * rn[j] + wv[7] * rn[j + 1] + wv[8] * rn[j + 2];
    }
    uint4 st;
    st.x = pack_bf(o[0], o[1]); st.y = pack_bf(o[2], o[3]);
    st.z = pack_bf(o[4], o[5]); st.w = pack_bf(o[6], o[7]);
    *reinterpret_cast<uint4*>(p + (size_t)y * W_ + x0) = st;
#pragma unroll
    for (int j = 0; j < 10; ++j) { rm[j] = rc[j]; rc[j] = rn[j]; }
    const int ny = y + 2;
    if (ny <= y0 + 31) {
      load_row(ny, rn);
    } else if (ny == y0 + 32) {
#pragma unroll
      for (int j = 0; j < 10; ++j) rn[j] = rb[j];
    }
  }
}

// ---------------- K5: reduce partials, scale by inv norms, softmax ----------
__global__ __launch_bounds__(256) void k_softmax(
    const float* __restrict__ part, const float* __restrict__ ssbuf,
    float* __restrict__ attn_out) {
  __shared__ float red[2][4][32];
  const int tid = threadIdx.x;
  {
    const int r2 = tid >> 7;          // 0..1: row within block
    const int loc = tid & 127;
    const int sg = loc >> 5;          // 0..3: split group
    const int j = loc & 31;
    const int R = blockIdx.x * 2 + r2;
    float v = 0.f;
#pragma unroll 8
    for (int s = sg; s < SPLITS_; s += 4)
      v += part[(size_t)s * (B_ * HEAD_ * 1024) + R * 32 + j];
    red[r2][sg][j] = v;
  }
  __syncthreads();
  if (tid < 64) {
    const int r2 = tid >> 5, j = tid & 31;
    const int R = blockIdx.x * 2 + r2;
    const int b = R / 96, rem = R % 96;
    const int h = rem / 32, i = rem % 32;
    float v = red[r2][0][j] + red[r2][1][j] + red[r2][2][j] + red[r2][3][j];
    const float ssq = ssbuf[b * 192 + h * 32 + i];
    const float ssk = ssbuf[b * 192 + 96 + h * 32 + j];
    v *= (1.0f / fmaxf(sqrtf(ssq), EPS_)) * (1.0f / fmaxf(sqrtf(ssk), EPS_));
    float m = v;
#pragma unroll
    for (int off = 16; off > 0; off >>= 1) m = fmaxf(m, __shfl_xor(m, off, 32));
    const float e = __expf(v - m);
    float s = e;
#pragma unroll
    for (int off = 16; off > 0; off >>= 1) s += __shfl_xor(s, off, 32);
    attn_out[R * 32 + j] = e / s;
  }
}

// ---------------- K6: M_b = proj_w o attn  (per-batch 96x96, bf16) ----------
__global__ __launch_bounds__(256) void k_M(
    const float* __restrict__ attn, const float* __restrict__ proj_w,
    unsigned short* __restrict__ Mbf) {
  const int b = blockIdx.x, h = blockIdx.y;
  const int tid = threadIdx.x;
  __shared__ float As[1024];          // attn[b,h][i][j]
  __shared__ float Pw[C_ * 32];       // proj_w[o][h*32+i]
  for (int l = tid; l < 1024; l += 256)
    As[l] = attn[((size_t)b * HEAD_ + h) * 1024 + l];
  for (int l = tid; l < C_ * 32; l += 256)
    Pw[l] = proj_w[(l >> 5) * C_ + h * 32 + (l & 31)];
  __syncthreads();
  for (int e = tid; e < C_ * 32; e += 256) {
    const int o = e >> 5, j = e & 31;
    float s = 0.f;
#pragma unroll
    for (int i = 0; i < 32; ++i) s += Pw[o * 32 + i] * As[i * 32 + j];
    Mbf[(size_t)b * C_ * C_ + o * C_ + h * 32 + j] = f2bf(s);
  }
}

// ---------------- K7: out = M_b @ v + proj_b via MFMA, swapped layout -------
__global__ __launch_bounds__(256) void k7_mfma(
    const unsigned short* __restrict__ A /* workspace base */,
    const unsigned short* __restrict__ Mbf,
    const float* __restrict__ bias, float* __restrict__ out) {
  const int tid = threadIdx.x;
  const int b = blockIdx.y;
  const int lane = tid & 63;
  const int wv = tid >> 6;
  const int l15 = lane & 15, quad = lane >> 4;
  const int pixbase = blockIdx.x * 64 + wv * 16;
  const unsigned short* vcol = A + ((size_t)(b * C3_ + 2 * C_)) * N_ + pixbase + l15;
  const unsigned short* Mb = Mbf + (size_t)b * C_ * C_;
  short8 afr[3];
#pragma unroll
  for (int kc = 0; kc < 3; ++kc) {
#pragma unroll
    for (int u = 0; u < 8; ++u)
      afr[kc][u] = (short)vcol[(size_t)(kc * 32 + quad * 8 + u) * N_];
  }
  f32x4 acc[6];
#pragma unroll
  for (int m = 0; m < 6; ++m) acc[m] = (f32x4){0.f, 0.f, 0.f, 0.f};
#pragma unroll
  for (int m = 0; m < 6; ++m) {
#pragma unroll
    for (int kc = 0; kc < 3; ++kc) {
      const short8 mfr = *reinterpret_cast<const short8*>(
          Mb + (m * 16 + l15) * C_ + kc * 32 + quad * 8);
      acc[m] = __builtin_amdgcn_mfma_f32_16x16x32_bf16(afr[kc], mfr, acc[m], 0, 0, 0);
    }
  }
  float* ob = out + (size_t)b * C_ * N_ + pixbase + quad * 4;
#pragma unroll
  for (int m = 0; m < 6; ++m) {
    const float bv = bias[m * 16 + l15];
    f32x4 st;
#pragma unroll
    for (int r = 0; r < 4; ++r) st[r] = acc[m][r] + bv;
    *reinterpret_cast<f32x4*>(ob + (size_t)(m * 16 + l15) * N_) = st;
  }
}

extern "C" void kernel_launch(void* const* d_in, const int* in_sizes, int n_in,
                              void* d_out, int out_size, void* d_ws, size_t ws_size,
                              hipStream_t stream) {
  const float* x      = (const float*)d_in[0];
  const float* qkv_w  = (const float*)d_in[1];
  const float* qkv_b  = (const float*)d_in[2];
  const float* dw_w   = (const float*)d_in[3];
  const float* dw_b   = (const float*)d_in[4];
  const float* proj_w = (const float*)d_in[5];
  const float* proj_b = (const float*)d_in[6];

  float* out      = (float*)d_out;                       // [4,96,256,256]
  float* attn_out = out + (size_t)B_ * C_ * N_;          // [4,3,32,32]

  // Workspace: A 151MB | ssbuf 3KB | part 1.5MB | Mbf 74KB
  unsigned short* A = (unsigned short*)d_ws;
  float* ssbuf = (float*)(A + (size_t)B_ * C3_ * N_);
  float* part  = ssbuf + 768;
  unsigned short* Mbf = (unsigned short*)(part + (size_t)SPLITS_ * B_ * HEAD_ * 1024);

  hipMemsetAsync(ssbuf, 0, 768 * sizeof(float), stream);
  k1_mfma<<<dim3(N_ / 128, B_), 512, 0, stream>>>(x, qkv_w, qkv_b, A);
  k_dwqk<<<dim3(SPLITS_, HEAD_, B_), 512, 0, stream>>>(A, dw_w, dw_b, part, ssbuf);
  k_dwv<<<B_ * 96, 256, 0, stream>>>(A, dw_w, dw_b);
  k_softmax<<<192, 256, 0, stream>>>(part, ssbuf, attn_out);
  k_M<<<dim3(B_, HEAD_), 256, 0, stream>>>(attn_out, proj_w, Mbf);
  k7_mfma<<<dim3(N_ / 64, B_), 256, 0, stream>>>(A, Mbf, proj_b, out);
}

// Round 6
// 408.079 us; speedup vs baseline: 1.3524x; 1.3524x over previous
//
#include <hip/hip_runtime.h>
#include <hip/hip_bf16.h>

// Problem dims (StandardAttention): x[4,96,256,256], heads=3
#define B_  4
#define C_  96
#define H_  256
#define W_  256
#define N_  (H_*W_)      // 65536
#define C3_ 288
#define HEAD_ 3
#define HC_ 32
#define EPS_ 1e-12f
#define XP_ 104          // padded LDS row stride (ushorts): 52 words -> 2 lanes/bank (free)
#define SPLITS_ 128      // split-K segments for QK^T

typedef __attribute__((ext_vector_type(8))) short short8;
typedef __attribute__((ext_vector_type(4))) float f32x4;

// ---- bf16 helpers (raw ushort storage) -------------------------------------
__device__ __forceinline__ unsigned short f2bf(float f) {
  unsigned u = __float_as_uint(f);
  u += 0x7fffu + ((u >> 16) & 1u);      // round-to-nearest-even
  return (unsigned short)(u >> 16);
}
__device__ __forceinline__ float bf2f(unsigned short h) {
  return __uint_as_float((unsigned)h << 16);
}
__device__ __forceinline__ float bf_lo(unsigned u) { return __uint_as_float(u << 16); }
__device__ __forceinline__ float bf_hi(unsigned u) { return __uint_as_float(u & 0xffff0000u); }
__device__ __forceinline__ unsigned pack_bf(float a, float b) {
  return (unsigned)f2bf(a) | ((unsigned)f2bf(b) << 16);
}
// packed f32x2 -> bf16x2 in one VALU inst (RNE)
__device__ __forceinline__ unsigned cvt_pk(float lo, float hi) {
  unsigned r;
  asm("v_cvt_pk_bf16_f32 %0, %1, %2" : "=v"(r) : "v"(lo), "v"(hi));
  return r;
}

// ---------------- K1: qkv = qkv_w @ x + qkv_b via MFMA (PERSISTENT) ---------
// R1-proven per-tile compute/store shape (A=W from LDS, B=x in regs, scalar
// 2B stores). NEW: 512 persistent blocks (2/CU) grid-stride over all 2048
// (tile,batch) units -> W staged in LDS ONCE per block instead of once per
// tile (staging VALU + W L2 refetch / 4). cvt_pk packing for x-loads and
// epilogue (VALU cut, store shape unchanged).
__global__ __launch_bounds__(512) void k1_mfma(
    const float* __restrict__ x, const float* __restrict__ wsrc,
    const float* __restrict__ bias, unsigned short* __restrict__ out) {
  __shared__ unsigned short Wl[C3_ * XP_];    // 59904 B
  __shared__ float Bl[C3_];
  const int tid = threadIdx.x;
  for (int i = tid; i < (C3_ * C_) / 2; i += 512) {
    const int o = i / 48, c2 = (i % 48) * 2;
    const float2 f = *reinterpret_cast<const float2*>(wsrc + o * 96 + c2);
    *reinterpret_cast<unsigned*>(&Wl[o * XP_ + c2]) = cvt_pk(f.x, f.y);
  }
  for (int i = tid; i < C3_; i += 512) Bl[i] = bias[i];
  __syncthreads();
  const int lane = tid & 63;
  const int wv = tid >> 6;                    // 0..7
  const int l15 = lane & 15, quad = lane >> 4;
  for (int t = blockIdx.x; t < 2048; t += 512) {
    const int b = t >> 9, tile = t & 511;
    const int gpix = tile * 128 + wv * 16 + l15;
    const float* xcol = x + (size_t)b * C_ * N_ + gpix;
    union { short8 s; unsigned u[4]; } bx[3];
#pragma unroll
    for (int kc = 0; kc < 3; ++kc) {
#pragma unroll
      for (int j = 0; j < 4; ++j) {
        const float f0 = xcol[(size_t)(kc * 32 + quad * 8 + 2 * j) * N_];
        const float f1 = xcol[(size_t)(kc * 32 + quad * 8 + 2 * j + 1) * N_];
        bx[kc].u[j] = cvt_pk(f0, f1);
      }
    }
    f32x4 acc[18];
#pragma unroll
    for (int m = 0; m < 18; ++m) acc[m] = (f32x4){0.f, 0.f, 0.f, 0.f};
#pragma unroll
    for (int m = 0; m < 18; ++m) {
#pragma unroll
      for (int kc = 0; kc < 3; ++kc) {
        const short8 afr = *reinterpret_cast<const short8*>(
            &Wl[(m * 16 + l15) * XP_ + kc * 32 + quad * 8]);
        acc[m] = __builtin_amdgcn_mfma_f32_16x16x32_bf16(afr, bx[kc].s, acc[m], 0, 0, 0);
      }
    }
    unsigned short* ob = out + (size_t)b * C3_ * N_ + gpix;
#pragma unroll
    for (int m = 0; m < 18; ++m) {
      const int chb = m * 16 + quad * 4;
      const unsigned pk0 = cvt_pk(acc[m][0] + Bl[chb], acc[m][1] + Bl[chb + 1]);
      const unsigned pk1 = cvt_pk(acc[m][2] + Bl[chb + 2], acc[m][3] + Bl[chb + 3]);
      ob[(size_t)chb * N_]       = (unsigned short)(pk0 & 0xffffu);
      ob[(size_t)(chb + 1) * N_] = (unsigned short)(pk0 >> 16);
      ob[(size_t)(chb + 2) * N_] = (unsigned short)(pk1 & 0xffffu);
      ob[(size_t)(chb + 3) * N_] = (unsigned short)(pk1 >> 16);
    }
  }
}

// ---------------- K2: 3x3 depthwise conv IN-PLACE, register-rolling ---------
__global__ __launch_bounds__(256) void k_dw_reg(
    unsigned short* a, const float* __restrict__ w9,
    const float* __restrict__ bias, float* __restrict__ inv) {
  const int bc = blockIdx.x;            // 0..1151
  const int ch = bc % C3_;
  unsigned short* p = a + (size_t)bc * N_;
  const int tid = threadIdx.x;
  const int tr = tid >> 5;              // 0..7 row segment
  const int tc = tid & 31;
  const int x0 = tc * 8;
  const int y0 = tr * 32;
  float wv[9];
#pragma unroll
  for (int i = 0; i < 9; ++i) wv[i] = w9[ch * 9 + i];
  const float bv = bias[ch];

  auto load_row = [&](int y, float* d) {
    if ((unsigned)y >= 256u) {
#pragma unroll
      for (int j = 0; j < 10; ++j) d[j] = 0.f;
      return;
    }
    const unsigned short* rp = p + (size_t)y * W_;
    const uint4 u = *reinterpret_cast<const uint4*>(rp + x0);
    d[1] = bf_lo(u.x); d[2] = bf_hi(u.x); d[3] = bf_lo(u.y); d[4] = bf_hi(u.y);
    d[5] = bf_lo(u.z); d[6] = bf_hi(u.z); d[7] = bf_lo(u.w); d[8] = bf_hi(u.w);
    d[0] = (tc > 0) ? bf2f(rp[x0 - 1]) : 0.f;
    d[9] = (tc < 31) ? bf2f(rp[x0 + 8]) : 0.f;
  };

  float rm[10], rc[10], rn[10], rb[10];
  load_row(y0 - 1, rm);
  load_row(y0, rc);
  load_row(y0 + 1, rn);
  load_row(y0 + 32, rb);     // bottom boundary: original data, pre-barrier
  __syncthreads();           // all preloads done before any write

  float ss = 0.f;
  for (int y = y0; y < y0 + 32; ++y) {
    float o[8];
#pragma unroll
    for (int j = 0; j < 8; ++j) {
      o[j] = bv + wv[0] * rm[j] + wv[1] * rm[j + 1] + wv[2] * rm[j + 2]
                + wv[3] * rc[j] + wv[4] * rc[j + 1] + wv[5] * rc[j + 2]
                + wv[6] * rn[j] + wv[7] * rn[j + 1] + wv[8] * rn[j + 2];
      ss += o[j] * o[j];
    }
    uint4 st;
    st.x = pack_bf(o[0], o[1]); st.y = pack_bf(o[2], o[3]);
    st.z = pack_bf(o[4], o[5]); st.w = pack_bf(o[6], o[7]);
    *reinterpret_cast<uint4*>(p + (size_t)y * W_ + x0) = st;
#pragma unroll
    for (int j = 0; j < 10; ++j) { rm[j] = rc[j]; rc[j] = rn[j]; }
    const int ny = y + 2;
    if (ny <= y0 + 31) {
      load_row(ny, rn);
    } else if (ny == y0 + 32) {
#pragma unroll
      for (int j = 0; j < 10; ++j) rn[j] = rb[j];
    }
  }
#pragma unroll
  for (int off = 32; off > 0; off >>= 1) ss += __shfl_down(ss, off, 64);
  __shared__ float red[4];
  if ((tid & 63) == 0) red[tid >> 6] = ss;
  __syncthreads();
  if (tid == 0 && ch < 192) {
    const float t = red[0] + red[1] + red[2] + red[3];
    const int b = bc / C3_;
    inv[b * 192 + ch] = 1.0f / fmaxf(sqrtf(t), EPS_);
  }
}

// ---------------- K4: QK^T via MFMA, split-K partials (no atomics) ----------
__global__ __launch_bounds__(256) void k_attn_mfma(
    const unsigned short* __restrict__ dw, float* __restrict__ part) {
  const int tid = threadIdx.x;
  const int lane = tid & 63;
  const int wv = tid >> 6;
  const int i0 = (wv >> 1) * 16, j0 = (wv & 1) * 16;
  const int h = blockIdx.y, b = blockIdx.z;
  const int n0 = blockIdx.x * (N_ / SPLITS_);    // 512-px segment
  const int l15 = lane & 15, quad = lane >> 4;
  const unsigned short* qrow =
      dw + ((size_t)(b * C3_ + h * HC_ + i0 + l15)) * N_ + n0 + quad * 8;
  const unsigned short* krow =
      dw + ((size_t)(b * C3_ + C_ + h * HC_ + j0 + l15)) * N_ + n0 + quad * 8;
  f32x4 acc = (f32x4){0.f, 0.f, 0.f, 0.f};
#pragma unroll 8
  for (int s = 0; s < N_ / SPLITS_; s += 32) {
    const short8 af = *reinterpret_cast<const short8*>(qrow + s);
    const short8 bf = *reinterpret_cast<const short8*>(krow + s);
    acc = __builtin_amdgcn_mfma_f32_16x16x32_bf16(af, bf, acc, 0, 0, 0);
  }
  float* pp = part + (size_t)blockIdx.x * (B_ * HEAD_ * 1024)
                   + ((size_t)(b * HEAD_ + h)) * 1024;
#pragma unroll
  for (int r = 0; r < 4; ++r)
    pp[(i0 + quad * 4 + r) * 32 + j0 + l15] = acc[r];
}

// ---------------- K5: reduce partials, scale by inv norms, softmax ----------
__global__ __launch_bounds__(256) void k_softmax(
    const float* __restrict__ part, const float* __restrict__ inv,
    float* __restrict__ attn_out) {
  __shared__ float red[2][4][32];
  const int tid = threadIdx.x;
  {
    const int r2 = tid >> 7;          // 0..1: row within block
    const int loc = tid & 127;
    const int sg = loc >> 5;          // 0..3: split group
    const int j = loc & 31;
    const int R = blockIdx.x * 2 + r2;
    float v = 0.f;
#pragma unroll 8
    for (int s = sg; s < SPLITS_; s += 4)
      v += part[(size_t)s * (B_ * HEAD_ * 1024) + R * 32 + j];
    red[r2][sg][j] = v;
  }
  __syncthreads();
  if (tid < 64) {
    const int r2 = tid >> 5, j = tid & 31;
    const int R = blockIdx.x * 2 + r2;
    const int b = R / 96, rem = R % 96;
    const int h = rem / 32, i = rem % 32;
    float v = red[r2][0][j] + red[r2][1][j] + red[r2][2][j] + red[r2][3][j];
    v *= inv[b * 192 + h * 32 + i] * inv[b * 192 + 96 + h * 32 + j];  // TEMP=1
    float m = v;
#pragma unroll
    for (int off = 16; off > 0; off >>= 1) m = fmaxf(m, __shfl_xor(m, off, 32));
    const float e = __expf(v - m);
    float s = e;
#pragma unroll
    for (int off = 16; off > 0; off >>= 1) s += __shfl_xor(s, off, 32);
    attn_out[R * 32 + j] = e / s;
  }
}

// ---------------- K6: M_b = proj_w o attn  (per-batch 96x96, bf16) ----------
__global__ __launch_bounds__(256) void k_M(
    const float* __restrict__ attn, const float* __restrict__ proj_w,
    unsigned short* __restrict__ Mbf) {
  const int b = blockIdx.x, h = blockIdx.y;
  const int tid = threadIdx.x;
  __shared__ float As[1024];          // attn[b,h][i][j]
  __shared__ float Pw[C_ * 32];       // proj_w[o][h*32+i]
  for (int l = tid; l < 1024; l += 256)
    As[l] = attn[((size_t)b * HEAD_ + h) * 1024 + l];
  for (int l = tid; l < C_ * 32; l += 256)
    Pw[l] = proj_w[(l >> 5) * C_ + h * 32 + (l & 31)];
  __syncthreads();
  for (int e = tid; e < C_ * 32; e += 256) {
    const int o = e >> 5, j = e & 31;
    float s = 0.f;
#pragma unroll
    for (int i = 0; i < 32; ++i) s += Pw[o * 32 + i] * As[i * 32 + j];
    Mbf[(size_t)b * C_ * C_ + o * C_ + h * 32 + j] = f2bf(s);
  }
}

// ---------------- K7: out = M_b @ v + proj_b via MFMA, swapped layout -------
// A-frag = v tile (pixels as M-rows), B-frag = M^T (18KB, L1-hot).
// D[pix][och]: 4 consecutive fp32 pixels per lane -> float4 stores.
__global__ __launch_bounds__(256) void k7_mfma(
    const unsigned short* __restrict__ A /* workspace base */,
    const unsigned short* __restrict__ Mbf,
    const float* __restrict__ bias, float* __restrict__ out) {
  const int tid = threadIdx.x;
  const int b = blockIdx.y;
  const int lane = tid & 63;
  const int wv = tid >> 6;
  const int l15 = lane & 15, quad = lane >> 4;
  const int pixbase = blockIdx.x * 64 + wv * 16;
  const unsigned short* vcol = A + ((size_t)(b * C3_ + 2 * C_)) * N_ + pixbase + l15;
  const unsigned short* Mb = Mbf + (size_t)b * C_ * C_;
  short8 afr[3];
#pragma unroll
  for (int kc = 0; kc < 3; ++kc) {
#pragma unroll
    for (int u = 0; u < 8; ++u)
      afr[kc][u] = (short)vcol[(size_t)(kc * 32 + quad * 8 + u) * N_];
  }
  f32x4 acc[6];
#pragma unroll
  for (int m = 0; m < 6; ++m) acc[m] = (f32x4){0.f, 0.f, 0.f, 0.f};
#pragma unroll
  for (int m = 0; m < 6; ++m) {
#pragma unroll
    for (int kc = 0; kc < 3; ++kc) {
      // B-frag = M^T: k = in_ch quad*8+u, col = out_ch m*16+l15
      const short8 mfr = *reinterpret_cast<const short8*>(
          Mb + (m * 16 + l15) * C_ + kc * 32 + quad * 8);
      acc[m] = __builtin_amdgcn_mfma_f32_16x16x32_bf16(afr[kc], mfr, acc[m], 0, 0, 0);
    }
  }
  float* ob = out + (size_t)b * C_ * N_ + pixbase + quad * 4;
#pragma unroll
  for (int m = 0; m < 6; ++m) {
    const float bv = bias[m * 16 + l15];
    f32x4 st;
#pragma unroll
    for (int r = 0; r < 4; ++r) st[r] = acc[m][r] + bv;
    *reinterpret_cast<f32x4*>(ob + (size_t)(m * 16 + l15) * N_) = st;
  }
}

extern "C" void kernel_launch(void* const* d_in, const int* in_sizes, int n_in,
                              void* d_out, int out_size, void* d_ws, size_t ws_size,
                              hipStream_t stream) {
  const float* x      = (const float*)d_in[0];
  const float* qkv_w  = (const float*)d_in[1];
  const float* qkv_b  = (const float*)d_in[2];
  const float* dw_w   = (const float*)d_in[3];
  const float* dw_b   = (const float*)d_in[4];
  const float* proj_w = (const float*)d_in[5];
  const float* proj_b = (const float*)d_in[6];

  float* out      = (float*)d_out;                       // [4,96,256,256]
  float* attn_out = out + (size_t)B_ * C_ * N_;          // [4,3,32,32]

  // Workspace: A 151MB | inv 3KB | part 6.3MB | Mbf 74KB
  unsigned short* A = (unsigned short*)d_ws;
  float* inv   = (float*)(A + (size_t)B_ * C3_ * N_);
  float* part  = inv + 768;
  unsigned short* Mbf = (unsigned short*)(part + (size_t)SPLITS_ * B_ * HEAD_ * 1024);

  k1_mfma<<<512, 512, 0, stream>>>(x, qkv_w, qkv_b, A);
  k_dw_reg<<<B_ * C3_, 256, 0, stream>>>(A, dw_w, dw_b, inv);
  k_attn_mfma<<<dim3(SPLITS_, HEAD_, B_), 256, 0, stream>>>(A, part);
  k_softmax<<<192, 256, 0, stream>>>(part, inv, attn_out);
  k_M<<<dim3(B_, HEAD_), 256, 0, stream>>>(attn_out, proj_w, Mbf);
  k7_mfma<<<dim3(N_ / 64, B_), 256, 0, stream>>>(A, Mbf, proj_b, out);
}

// Round 7
// 338.148 us; speedup vs baseline: 1.6321x; 1.2068x over previous
//
#include <hip/hip_runtime.h>
#include <hip/hip_bf16.h>

// Problem dims (StandardAttention): x[4,96,256,256], heads=3
#define B_  4
#define C_  96
#define H_  256
#define W_  256
#define N_  (H_*W_)      // 65536
#define C3_ 288
#define HEAD_ 3
#define HC_ 32
#define EPS_ 1e-12f
#define XP_ 104          // padded LDS row stride (ushorts): 52 words -> 2 lanes/bank (free)
#define SPLITS_ 128      // split-K segments for QK^T

typedef __attribute__((ext_vector_type(8))) short short8;
typedef __attribute__((ext_vector_type(4))) float f32x4;

// ---- bf16 helpers (raw ushort storage) -------------------------------------
__device__ __forceinline__ unsigned short f2bf(float f) {
  unsigned u = __float_as_uint(f);
  u += 0x7fffu + ((u >> 16) & 1u);      // round-to-nearest-even
  return (unsigned short)(u >> 16);
}
__device__ __forceinline__ float bf2f(unsigned short h) {
  return __uint_as_float((unsigned)h << 16);
}
__device__ __forceinline__ float bf_lo(unsigned u) { return __uint_as_float(u << 16); }
__device__ __forceinline__ float bf_hi(unsigned u) { return __uint_as_float(u & 0xffff0000u); }
__device__ __forceinline__ unsigned pack_bf(float a, float b) {
  return (unsigned)f2bf(a) | ((unsigned)f2bf(b) << 16);
}

// ---------------- K1: qkv = qkv_w @ x + qkv_b via MFMA ----------------------
// R1-proven form, FROZEN (85.6 us measured; every restructure since lost):
// 512 thr = 8 waves x 16 px; W staged once in LDS (padded rows, fp32->bf16
// on the fly); B-frags from global; scalar 2B stores; VGPR 52, acc in AGPRs.
__global__ __launch_bounds__(512) void k1_mfma(
    const float* __restrict__ x, const float* __restrict__ wsrc,
    const float* __restrict__ bias, unsigned short* __restrict__ out) {
  __shared__ unsigned short Wl[C3_ * XP_];    // 59904 B
  __shared__ float Bl[C3_];
  const int tid = threadIdx.x;
  const int b = blockIdx.y;
  for (int i = tid; i < C3_ * C_; i += 512)
    Wl[(i / 96) * XP_ + (i % 96)] = f2bf(wsrc[i]);
  for (int i = tid; i < C3_; i += 512) Bl[i] = bias[i];
  __syncthreads();
  const int lane = tid & 63;
  const int wv = tid >> 6;                    // 0..7
  const int l15 = lane & 15, quad = lane >> 4;
  const int gpix = blockIdx.x * 128 + wv * 16 + l15;
  const float* xcol = x + (size_t)b * C_ * N_ + gpix;
  short8 bfr[3];
#pragma unroll
  for (int kc = 0; kc < 3; ++kc) {
#pragma unroll
    for (int u = 0; u < 8; ++u)
      bfr[kc][u] = (short)f2bf(xcol[(size_t)(kc * 32 + quad * 8 + u) * N_]);
  }
  f32x4 acc[18];
#pragma unroll
  for (int m = 0; m < 18; ++m) acc[m] = (f32x4){0.f, 0.f, 0.f, 0.f};
#pragma unroll
  for (int m = 0; m < 18; ++m) {
#pragma unroll
    for (int kc = 0; kc < 3; ++kc) {
      const short8 afr = *reinterpret_cast<const short8*>(
          &Wl[(m * 16 + l15) * XP_ + kc * 32 + quad * 8]);
      acc[m] = __builtin_amdgcn_mfma_f32_16x16x32_bf16(afr, bfr[kc], acc[m], 0, 0, 0);
    }
  }
  unsigned short* ob = out + (size_t)b * C3_ * N_ + gpix;
#pragma unroll
  for (int m = 0; m < 18; ++m) {
    const int chb = m * 16 + quad * 4;
#pragma unroll
    for (int r = 0; r < 4; ++r)
      ob[(size_t)(chb + r) * N_] = f2bf(acc[m][r] + Bl[chb + r]);
  }
}

// ---------------- K2: 3x3 depthwise conv IN-PLACE, register-rolling ---------
// NEW: halo values via __shfl from neighbor lanes (they already hold them in
// registers) instead of 2 scalar 2B global loads per row -> VMEM load insts
// per row 3 -> 1 (halo was 40% of load issue for 1.5% of bytes).
__global__ __launch_bounds__(256) void k_dw_reg(
    unsigned short* a, const float* __restrict__ w9,
    const float* __restrict__ bias, float* __restrict__ inv) {
  const int bc = blockIdx.x;            // 0..1151
  const int ch = bc % C3_;
  unsigned short* p = a + (size_t)bc * N_;
  const int tid = threadIdx.x;
  const int tr = tid >> 5;              // 0..7 row segment
  const int tc = tid & 31;
  const int x0 = tc * 8;
  const int y0 = tr * 32;
  float wv[9];
#pragma unroll
  for (int i = 0; i < 9; ++i) wv[i] = w9[ch * 9 + i];
  const float bv = bias[ch];

  auto load_row = [&](int y, float* d) {
    if ((unsigned)y >= 256u) {
#pragma unroll
      for (int j = 1; j < 9; ++j) d[j] = 0.f;
    } else {
      const unsigned short* rp = p + (size_t)y * W_;
      const uint4 u = *reinterpret_cast<const uint4*>(rp + x0);
      d[1] = bf_lo(u.x); d[2] = bf_hi(u.x); d[3] = bf_lo(u.y); d[4] = bf_hi(u.y);
      d[5] = bf_lo(u.z); d[6] = bf_hi(u.z); d[7] = bf_lo(u.w); d[8] = bf_hi(u.w);
    }
    // converged: halo from neighbor lanes' registers (same 32-lane row group;
    // boundary lanes masked). lane tc-1's d[8] == x0-1, tc+1's d[1] == x0+8.
    const float left  = __shfl(d[8], (tid - 1) & 63, 64);
    const float right = __shfl(d[1], (tid + 1) & 63, 64);
    d[0] = (tc > 0)  ? left  : 0.f;
    d[9] = (tc < 31) ? right : 0.f;
  };

  float rm[10], rc[10], rn[10], rb[10];
  load_row(y0 - 1, rm);
  load_row(y0, rc);
  load_row(y0 + 1, rn);
  load_row(y0 + 32, rb);     // bottom boundary: original data, pre-barrier
  __syncthreads();           // all preloads done before any write

  float ss = 0.f;
  for (int y = y0; y < y0 + 32; ++y) {
    float o[8];
#pragma unroll
    for (int j = 0; j < 8; ++j) {
      o[j] = bv + wv[0] * rm[j] + wv[1] * rm[j + 1] + wv[2] * rm[j + 2]
                + wv[3] * rc[j] + wv[4] * rc[j + 1] + wv[5] * rc[j + 2]
                + wv[6] * rn[j] + wv[7] * rn[j + 1] + wv[8] * rn[j + 2];
      ss += o[j] * o[j];
    }
    uint4 st;
    st.x = pack_bf(o[0], o[1]); st.y = pack_bf(o[2], o[3]);
    st.z = pack_bf(o[4], o[5]); st.w = pack_bf(o[6], o[7]);
    *reinterpret_cast<uint4*>(p + (size_t)y * W_ + x0) = st;
#pragma unroll
    for (int j = 0; j < 10; ++j) { rm[j] = rc[j]; rc[j] = rn[j]; }
    const int ny = y + 2;
    if (ny <= y0 + 31) {
      load_row(ny, rn);
    } else if (ny == y0 + 32) {
#pragma unroll
      for (int j = 0; j < 10; ++j) rn[j] = rb[j];
    }
  }
#pragma unroll
  for (int off = 32; off > 0; off >>= 1) ss += __shfl_down(ss, off, 64);
  __shared__ float red[4];
  if ((tid & 63) == 0) red[tid >> 6] = ss;
  __syncthreads();
  if (tid == 0 && ch < 192) {
    const float t = red[0] + red[1] + red[2] + red[3];
    const int b = bc / C3_;
    inv[b * 192 + ch] = 1.0f / fmaxf(sqrtf(t), EPS_);
  }
}

// ---------------- K4: QK^T via MFMA, split-K partials (no atomics) ----------
__global__ __launch_bounds__(256) void k_attn_mfma(
    const unsigned short* __restrict__ dw, float* __restrict__ part) {
  const int tid = threadIdx.x;
  const int lane = tid & 63;
  const int wv = tid >> 6;
  const int i0 = (wv >> 1) * 16, j0 = (wv & 1) * 16;
  const int h = blockIdx.y, b = blockIdx.z;
  const int n0 = blockIdx.x * (N_ / SPLITS_);    // 512-px segment
  const int l15 = lane & 15, quad = lane >> 4;
  const unsigned short* qrow =
      dw + ((size_t)(b * C3_ + h * HC_ + i0 + l15)) * N_ + n0 + quad * 8;
  const unsigned short* krow =
      dw + ((size_t)(b * C3_ + C_ + h * HC_ + j0 + l15)) * N_ + n0 + quad * 8;
  f32x4 acc = (f32x4){0.f, 0.f, 0.f, 0.f};
#pragma unroll 8
  for (int s = 0; s < N_ / SPLITS_; s += 32) {
    const short8 af = *reinterpret_cast<const short8*>(qrow + s);
    const short8 bf = *reinterpret_cast<const short8*>(krow + s);
    acc = __builtin_amdgcn_mfma_f32_16x16x32_bf16(af, bf, acc, 0, 0, 0);
  }
  float* pp = part + (size_t)blockIdx.x * (B_ * HEAD_ * 1024)
                   + ((size_t)(b * HEAD_ + h)) * 1024;
#pragma unroll
  for (int r = 0; r < 4; ++r)
    pp[(i0 + quad * 4 + r) * 32 + j0 + l15] = acc[r];
}

// ---------------- K5: reduce partials, scale by inv norms, softmax ----------
__global__ __launch_bounds__(256) void k_softmax(
    const float* __restrict__ part, const float* __restrict__ inv,
    float* __restrict__ attn_out) {
  __shared__ float red[2][4][32];
  const int tid = threadIdx.x;
  {
    const int r2 = tid >> 7;          // 0..1: row within block
    const int loc = tid & 127;
    const int sg = loc >> 5;          // 0..3: split group
    const int j = loc & 31;
    const int R = blockIdx.x * 2 + r2;
    float v = 0.f;
#pragma unroll 8
    for (int s = sg; s < SPLITS_; s += 4)
      v += part[(size_t)s * (B_ * HEAD_ * 1024) + R * 32 + j];
    red[r2][sg][j] = v;
  }
  __syncthreads();
  if (tid < 64) {
    const int r2 = tid >> 5, j = tid & 31;
    const int R = blockIdx.x * 2 + r2;
    const int b = R / 96, rem = R % 96;
    const int h = rem / 32, i = rem % 32;
    float v = red[r2][0][j] + red[r2][1][j] + red[r2][2][j] + red[r2][3][j];
    v *= inv[b * 192 + h * 32 + i] * inv[b * 192 + 96 + h * 32 + j];  // TEMP=1
    float m = v;
#pragma unroll
    for (int off = 16; off > 0; off >>= 1) m = fmaxf(m, __shfl_xor(m, off, 32));
    const float e = __expf(v - m);
    float s = e;
#pragma unroll
    for (int off = 16; off > 0; off >>= 1) s += __shfl_xor(s, off, 32);
    attn_out[R * 32 + j] = e / s;
  }
}

// ---------------- K6: M_b = proj_w o attn  (per-batch 96x96, bf16) ----------
__global__ __launch_bounds__(256) void k_M(
    const float* __restrict__ attn, const float* __restrict__ proj_w,
    unsigned short* __restrict__ Mbf) {
  const int b = blockIdx.x, h = blockIdx.y;
  const int tid = threadIdx.x;
  __shared__ float As[1024];          // attn[b,h][i][j]
  __shared__ float Pw[C_ * 32];       // proj_w[o][h*32+i]
  for (int l = tid; l < 1024; l += 256)
    As[l] = attn[((size_t)b * HEAD_ + h) * 1024 + l];
  for (int l = tid; l < C_ * 32; l += 256)
    Pw[l] = proj_w[(l >> 5) * C_ + h * 32 + (l & 31)];
  __syncthreads();
  for (int e = tid; e < C_ * 32; e += 256) {
    const int o = e >> 5, j = e & 31;
    float s = 0.f;
#pragma unroll
    for (int i = 0; i < 32; ++i) s += Pw[o * 32 + i] * As[i * 32 + j];
    Mbf[(size_t)b * C_ * C_ + o * C_ + h * 32 + j] = f2bf(s);
  }
}

// ---------------- K7: out = M_b @ v + proj_b via MFMA, swapped layout -------
// A-frag = v tile (pixels as M-rows), B-frag = M^T (18KB, L1-hot).
// D[pix][och]: 4 consecutive fp32 pixels per lane -> float4 stores.
__global__ __launch_bounds__(256) void k7_mfma(
    const unsigned short* __restrict__ A /* workspace base */,
    const unsigned short* __restrict__ Mbf,
    const float* __restrict__ bias, float* __restrict__ out) {
  const int tid = threadIdx.x;
  const int b = blockIdx.y;
  const int lane = tid & 63;
  const int wv = tid >> 6;
  const int l15 = lane & 15, quad = lane >> 4;
  const int pixbase = blockIdx.x * 64 + wv * 16;
  const unsigned short* vcol = A + ((size_t)(b * C3_ + 2 * C_)) * N_ + pixbase + l15;
  const unsigned short* Mb = Mbf + (size_t)b * C_ * C_;
  short8 afr[3];
#pragma unroll
  for (int kc = 0; kc < 3; ++kc) {
#pragma unroll
    for (int u = 0; u < 8; ++u)
      afr[kc][u] = (short)vcol[(size_t)(kc * 32 + quad * 8 + u) * N_];
  }
  f32x4 acc[6];
#pragma unroll
  for (int m = 0; m < 6; ++m) acc[m] = (f32x4){0.f, 0.f, 0.f, 0.f};
#pragma unroll
  for (int m = 0; m < 6; ++m) {
#pragma unroll
    for (int kc = 0; kc < 3; ++kc) {
      // B-frag = M^T: k = in_ch quad*8+u, col = out_ch m*16+l15
      const short8 mfr = *reinterpret_cast<const short8*>(
          Mb + (m * 16 + l15) * C_ + kc * 32 + quad * 8);
      acc[m] = __builtin_amdgcn_mfma_f32_16x16x32_bf16(afr[kc], mfr, acc[m], 0, 0, 0);
    }
  }
  float* ob = out + (size_t)b * C_ * N_ + pixbase + quad * 4;
#pragma unroll
  for (int m = 0; m < 6; ++m) {
    const float bv = bias[m * 16 + l15];
    f32x4 st;
#pragma unroll
    for (int r = 0; r < 4; ++r) st[r] = acc[m][r] + bv;
    *reinterpret_cast<f32x4*>(ob + (size_t)(m * 16 + l15) * N_) = st;
  }
}

extern "C" void kernel_launch(void* const* d_in, const int* in_sizes, int n_in,
                              void* d_out, int out_size, void* d_ws, size_t ws_size,
                              hipStream_t stream) {
  const float* x      = (const float*)d_in[0];
  const float* qkv_w  = (const float*)d_in[1];
  const float* qkv_b  = (const float*)d_in[2];
  const float* dw_w   = (const float*)d_in[3];
  const float* dw_b   = (const float*)d_in[4];
  const float* proj_w = (const float*)d_in[5];
  const float* proj_b = (const float*)d_in[6];

  float* out      = (float*)d_out;                       // [4,96,256,256]
  float* attn_out = out + (size_t)B_ * C_ * N_;          // [4,3,32,32]

  // Workspace: A 151MB | inv 3KB | part 6.3MB | Mbf 74KB
  unsigned short* A = (unsigned short*)d_ws;
  float* inv   = (float*)(A + (size_t)B_ * C3_ * N_);
  float* part  = inv + 768;
  unsigned short* Mbf = (unsigned short*)(part + (size_t)SPLITS_ * B_ * HEAD_ * 1024);

  k1_mfma<<<dim3(N_ / 128, B_), 512, 0, stream>>>(x, qkv_w, qkv_b, A);
  k_dw_reg<<<B_ * C3_, 256, 0, stream>>>(A, dw_w, dw_b, inv);
  k_attn_mfma<<<dim3(SPLITS_, HEAD_, B_), 256, 0, stream>>>(A, part);
  k_softmax<<<192, 256, 0, stream>>>(part, inv, attn_out);
  k_M<<<dim3(B_, HEAD_), 256, 0, stream>>>(attn_out, proj_w, Mbf);
  k7_mfma<<<dim3(N_ / 64, B_), 256, 0, stream>>>(A, Mbf, proj_b, out);
}

// Round 8
// 336.303 us; speedup vs baseline: 1.6410x; 1.0055x over previous
//
#include <hip/hip_runtime.h>
#include <hip/hip_bf16.h>

// Problem dims (StandardAttention): x[4,96,256,256], heads=3
#define B_  4
#define C_  96
#define H_  256
#define W_  256
#define N_  (H_*W_)      // 65536
#define C3_ 288
#define HEAD_ 3
#define HC_ 32
#define EPS_ 1e-12f
#define XP_ 104          // padded LDS row stride (ushorts): 52 words -> 2 lanes/bank (free)
#define SPLITS_ 128      // split-K segments for QK^T

typedef __attribute__((ext_vector_type(8))) short short8;
typedef __attribute__((ext_vector_type(4))) float f32x4;

// ---- bf16 helpers (raw ushort storage) -------------------------------------
__device__ __forceinline__ unsigned short f2bf(float f) {
  unsigned u = __float_as_uint(f);
  u += 0x7fffu + ((u >> 16) & 1u);      // round-to-nearest-even
  return (unsigned short)(u >> 16);
}
__device__ __forceinline__ float bf2f(unsigned short h) {
  return __uint_as_float((unsigned)h << 16);
}
__device__ __forceinline__ float bf_lo(unsigned u) { return __uint_as_float(u << 16); }
__device__ __forceinline__ float bf_hi(unsigned u) { return __uint_as_float(u & 0xffff0000u); }
__device__ __forceinline__ unsigned pack_bf(float a, float b) {
  return (unsigned)f2bf(a) | ((unsigned)f2bf(b) << 16);
}

// ---------------- K1: qkv = qkv_w @ x + qkv_b via MFMA ----------------------
// R1-proven form, FROZEN (85.6 us measured; every restructure since lost):
// 512 thr = 8 waves x 16 px; W staged once in LDS (padded rows, fp32->bf16
// on the fly); B-frags from global; scalar 2B stores; VGPR 52, acc in AGPRs.
__global__ __launch_bounds__(512) void k1_mfma(
    const float* __restrict__ x, const float* __restrict__ wsrc,
    const float* __restrict__ bias, unsigned short* __restrict__ out) {
  __shared__ unsigned short Wl[C3_ * XP_];    // 59904 B
  __shared__ float Bl[C3_];
  const int tid = threadIdx.x;
  const int b = blockIdx.y;
  for (int i = tid; i < C3_ * C_; i += 512)
    Wl[(i / 96) * XP_ + (i % 96)] = f2bf(wsrc[i]);
  for (int i = tid; i < C3_; i += 512) Bl[i] = bias[i];
  __syncthreads();
  const int lane = tid & 63;
  const int wv = tid >> 6;                    // 0..7
  const int l15 = lane & 15, quad = lane >> 4;
  const int gpix = blockIdx.x * 128 + wv * 16 + l15;
  const float* xcol = x + (size_t)b * C_ * N_ + gpix;
  short8 bfr[3];
#pragma unroll
  for (int kc = 0; kc < 3; ++kc) {
#pragma unroll
    for (int u = 0; u < 8; ++u)
      bfr[kc][u] = (short)f2bf(xcol[(size_t)(kc * 32 + quad * 8 + u) * N_]);
  }
  f32x4 acc[18];
#pragma unroll
  for (int m = 0; m < 18; ++m) acc[m] = (f32x4){0.f, 0.f, 0.f, 0.f};
#pragma unroll
  for (int m = 0; m < 18; ++m) {
#pragma unroll
    for (int kc = 0; kc < 3; ++kc) {
      const short8 afr = *reinterpret_cast<const short8*>(
          &Wl[(m * 16 + l15) * XP_ + kc * 32 + quad * 8]);
      acc[m] = __builtin_amdgcn_mfma_f32_16x16x32_bf16(afr, bfr[kc], acc[m], 0, 0, 0);
    }
  }
  unsigned short* ob = out + (size_t)b * C3_ * N_ + gpix;
#pragma unroll
  for (int m = 0; m < 18; ++m) {
    const int chb = m * 16 + quad * 4;
#pragma unroll
    for (int r = 0; r < 4; ++r)
      ob[(size_t)(chb + r) * N_] = f2bf(acc[m][r] + Bl[chb + r]);
  }
}

// ---------------- K2: 3x3 depthwise conv IN-PLACE, register-rolling ---------
// NEW this round: raw-prefetch pipeline. load_row split into load_raw (global
// uint4 only) and finish (convert + halo shfls). Raw load for row y+2 issued
// at TOP of iter y; finish applies to LAST iter's raw (already arrived) ->
// load->use distance goes from ~0 (shfl forced immediate vmcnt wait) to one
// full iteration of FMA work. In-place hazard analysis unchanged.
__global__ __launch_bounds__(256) void k_dw_reg(
    unsigned short* a, const float* __restrict__ w9,
    const float* __restrict__ bias, float* __restrict__ inv) {
  const int bc = blockIdx.x;            // 0..1151
  const int ch = bc % C3_;
  unsigned short* p = a + (size_t)bc * N_;
  const int tid = threadIdx.x;
  const int tr = tid >> 5;              // 0..7 row segment
  const int tc = tid & 31;
  const int x0 = tc * 8;
  const int y0 = tr * 32;
  float wv[9];
#pragma unroll
  for (int i = 0; i < 9; ++i) wv[i] = w9[ch * 9 + i];
  const float bv = bias[ch];

  auto load_raw = [&](int y) -> uint4 {
    if ((unsigned)y >= 256u) return make_uint4(0u, 0u, 0u, 0u);
    return *reinterpret_cast<const uint4*>(p + (size_t)y * W_ + x0);
  };
  auto finish = [&](const uint4& u, float* d) {
    d[1] = bf_lo(u.x); d[2] = bf_hi(u.x); d[3] = bf_lo(u.y); d[4] = bf_hi(u.y);
    d[5] = bf_lo(u.z); d[6] = bf_hi(u.z); d[7] = bf_lo(u.w); d[8] = bf_hi(u.w);
    // halo from neighbor lanes' registers (same 32-lane row group; boundary
    // lanes masked). lane tc-1's d[8] == x0-1, tc+1's d[1] == x0+8.
    const float left  = __shfl(d[8], (tid - 1) & 63, 64);
    const float right = __shfl(d[1], (tid + 1) & 63, 64);
    d[0] = (tc > 0)  ? left  : 0.f;
    d[9] = (tc < 31) ? right : 0.f;
  };

  float rm[10], rc[10], rn[10];
  finish(load_raw(y0 - 1), rm);
  finish(load_raw(y0), rc);
  uint4 rawn = load_raw(y0 + 1);        // row y0+1, finished at iter 0
  const uint4 rbr = load_raw(y0 + 32);  // bottom halo: ORIGINAL data, pre-barrier
  __syncthreads();                      // all preloads done before any write

  float ss = 0.f;
  for (int i = 0; i < 32; ++i) {
    const int y = y0 + i;
    // issue next raw load first (consumed next iteration) — wave-uniform select
    const uint4 rawnext = (i < 30) ? load_raw(y + 2) : rbr;
    finish(rawn, rn);                   // row y+1 (loaded last iteration)
    float o[8];
#pragma unroll
    for (int j = 0; j < 8; ++j) {
      o[j] = bv + wv[0] * rm[j] + wv[1] * rm[j + 1] + wv[2] * rm[j + 2]
                + wv[3] * rc[j] + wv[4] * rc[j + 1] + wv[5] * rc[j + 2]
                + wv[6] * rn[j] + wv[7] * rn[j + 1] + wv[8] * rn[j + 2];
      ss += o[j] * o[j];
    }
    uint4 st;
    st.x = pack_bf(o[0], o[1]); st.y = pack_bf(o[2], o[3]);
    st.z = pack_bf(o[4], o[5]); st.w = pack_bf(o[6], o[7]);
    *reinterpret_cast<uint4*>(p + (size_t)y * W_ + x0) = st;
#pragma unroll
    for (int j = 0; j < 10; ++j) { rm[j] = rc[j]; rc[j] = rn[j]; }
    rawn = rawnext;
  }
#pragma unroll
  for (int off = 32; off > 0; off >>= 1) ss += __shfl_down(ss, off, 64);
  __shared__ float red[4];
  if ((tid & 63) == 0) red[tid >> 6] = ss;
  __syncthreads();
  if (tid == 0 && ch < 192) {
    const float t = red[0] + red[1] + red[2] + red[3];
    const int b = bc / C3_;
    inv[b * 192 + ch] = 1.0f / fmaxf(sqrtf(t), EPS_);
  }
}

// ---------------- K4: QK^T via MFMA, split-K partials (no atomics) ----------
__global__ __launch_bounds__(256) void k_attn_mfma(
    const unsigned short* __restrict__ dw, float* __restrict__ part) {
  const int tid = threadIdx.x;
  const int lane = tid & 63;
  const int wv = tid >> 6;
  const int i0 = (wv >> 1) * 16, j0 = (wv & 1) * 16;
  const int h = blockIdx.y, b = blockIdx.z;
  const int n0 = blockIdx.x * (N_ / SPLITS_);    // 512-px segment
  const int l15 = lane & 15, quad = lane >> 4;
  const unsigned short* qrow =
      dw + ((size_t)(b * C3_ + h * HC_ + i0 + l15)) * N_ + n0 + quad * 8;
  const unsigned short* krow =
      dw + ((size_t)(b * C3_ + C_ + h * HC_ + j0 + l15)) * N_ + n0 + quad * 8;
  f32x4 acc = (f32x4){0.f, 0.f, 0.f, 0.f};
#pragma unroll 8
  for (int s = 0; s < N_ / SPLITS_; s += 32) {
    const short8 af = *reinterpret_cast<const short8*>(qrow + s);
    const short8 bf = *reinterpret_cast<const short8*>(krow + s);
    acc = __builtin_amdgcn_mfma_f32_16x16x32_bf16(af, bf, acc, 0, 0, 0);
  }
  float* pp = part + (size_t)blockIdx.x * (B_ * HEAD_ * 1024)
                   + ((size_t)(b * HEAD_ + h)) * 1024;
#pragma unroll
  for (int r = 0; r < 4; ++r)
    pp[(i0 + quad * 4 + r) * 32 + j0 + l15] = acc[r];
}

// ---------------- K5: reduce partials, scale by inv norms, softmax ----------
__global__ __launch_bounds__(256) void k_softmax(
    const float* __restrict__ part, const float* __restrict__ inv,
    float* __restrict__ attn_out) {
  __shared__ float red[2][4][32];
  const int tid = threadIdx.x;
  {
    const int r2 = tid >> 7;          // 0..1: row within block
    const int loc = tid & 127;
    const int sg = loc >> 5;          // 0..3: split group
    const int j = loc & 31;
    const int R = blockIdx.x * 2 + r2;
    float v = 0.f;
#pragma unroll 8
    for (int s = sg; s < SPLITS_; s += 4)
      v += part[(size_t)s * (B_ * HEAD_ * 1024) + R * 32 + j];
    red[r2][sg][j] = v;
  }
  __syncthreads();
  if (tid < 64) {
    const int r2 = tid >> 5, j = tid & 31;
    const int R = blockIdx.x * 2 + r2;
    const int b = R / 96, rem = R % 96;
    const int h = rem / 32, i = rem % 32;
    float v = red[r2][0][j] + red[r2][1][j] + red[r2][2][j] + red[r2][3][j];
    v *= inv[b * 192 + h * 32 + i] * inv[b * 192 + 96 + h * 32 + j];  // TEMP=1
    float m = v;
#pragma unroll
    for (int off = 16; off > 0; off >>= 1) m = fmaxf(m, __shfl_xor(m, off, 32));
    const float e = __expf(v - m);
    float s = e;
#pragma unroll
    for (int off = 16; off > 0; off >>= 1) s += __shfl_xor(s, off, 32);
    attn_out[R * 32 + j] = e / s;
  }
}

// ---------------- K6: M_b = proj_w o attn  (per-batch 96x96, bf16) ----------
__global__ __launch_bounds__(256) void k_M(
    const float* __restrict__ attn, const float* __restrict__ proj_w,
    unsigned short* __restrict__ Mbf) {
  const int b = blockIdx.x, h = blockIdx.y;
  const int tid = threadIdx.x;
  __shared__ float As[1024];          // attn[b,h][i][j]
  __shared__ float Pw[C_ * 32];       // proj_w[o][h*32+i]
  for (int l = tid; l < 1024; l += 256)
    As[l] = attn[((size_t)b * HEAD_ + h) * 1024 + l];
  for (int l = tid; l < C_ * 32; l += 256)
    Pw[l] = proj_w[(l >> 5) * C_ + h * 32 + (l & 31)];
  __syncthreads();
  for (int e = tid; e < C_ * 32; e += 256) {
    const int o = e >> 5, j = e & 31;
    float s = 0.f;
#pragma unroll
    for (int i = 0; i < 32; ++i) s += Pw[o * 32 + i] * As[i * 32 + j];
    Mbf[(size_t)b * C_ * C_ + o * C_ + h * 32 + j] = f2bf(s);
  }
}

// ---------------- K7: out = M_b @ v + proj_b via MFMA, swapped layout -------
// A-frag = v tile (pixels as M-rows), B-frag = M^T (18KB, L1-hot).
// D[pix][och]: 4 consecutive fp32 pixels per lane -> float4 stores.
__global__ __launch_bounds__(256) void k7_mfma(
    const unsigned short* __restrict__ A /* workspace base */,
    const unsigned short* __restrict__ Mbf,
    const float* __restrict__ bias, float* __restrict__ out) {
  const int tid = threadIdx.x;
  const int b = blockIdx.y;
  const int lane = tid & 63;
  const int wv = tid >> 6;
  const int l15 = lane & 15, quad = lane >> 4;
  const int pixbase = blockIdx.x * 64 + wv * 16;
  const unsigned short* vcol = A + ((size_t)(b * C3_ + 2 * C_)) * N_ + pixbase + l15;
  const unsigned short* Mb = Mbf + (size_t)b * C_ * C_;
  short8 afr[3];
#pragma unroll
  for (int kc = 0; kc < 3; ++kc) {
#pragma unroll
    for (int u = 0; u < 8; ++u)
      afr[kc][u] = (short)vcol[(size_t)(kc * 32 + quad * 8 + u) * N_];
  }
  f32x4 acc[6];
#pragma unroll
  for (int m = 0; m < 6; ++m) acc[m] = (f32x4){0.f, 0.f, 0.f, 0.f};
#pragma unroll
  for (int m = 0; m < 6; ++m) {
#pragma unroll
    for (int kc = 0; kc < 3; ++kc) {
      // B-frag = M^T: k = in_ch quad*8+u, col = out_ch m*16+l15
      const short8 mfr = *reinterpret_cast<const short8*>(
          Mb + (m * 16 + l15) * C_ + kc * 32 + quad * 8);
      acc[m] = __builtin_amdgcn_mfma_f32_16x16x32_bf16(afr[kc], mfr, acc[m], 0, 0, 0);
    }
  }
  float* ob = out + (size_t)b * C_ * N_ + pixbase + quad * 4;
#pragma unroll
  for (int m = 0; m < 6; ++m) {
    const float bv = bias[m * 16 + l15];
    f32x4 st;
#pragma unroll
    for (int r = 0; r < 4; ++r) st[r] = acc[m][r] + bv;
    *reinterpret_cast<f32x4*>(ob + (size_t)(m * 16 + l15) * N_) = st;
  }
}

extern "C" void kernel_launch(void* const* d_in, const int* in_sizes, int n_in,
                              void* d_out, int out_size, void* d_ws, size_t ws_size,
                              hipStream_t stream) {
  const float* x      = (const float*)d_in[0];
  const float* qkv_w  = (const float*)d_in[1];
  const float* qkv_b  = (const float*)d_in[2];
  const float* dw_w   = (const float*)d_in[3];
  const float* dw_b   = (const float*)d_in[4];
  const float* proj_w = (const float*)d_in[5];
  const float* proj_b = (const float*)d_in[6];

  float* out      = (float*)d_out;                       // [4,96,256,256]
  float* attn_out = out + (size_t)B_ * C_ * N_;          // [4,3,32,32]

  // Workspace: A 151MB | inv 3KB | part 6.3MB | Mbf 74KB
  unsigned short* A = (unsigned short*)d_ws;
  float* inv   = (float*)(A + (size_t)B_ * C3_ * N_);
  float* part  = inv + 768;
  unsigned short* Mbf = (unsigned short*)(part + (size_t)SPLITS_ * B_ * HEAD_ * 1024);

  k1_mfma<<<dim3(N_ / 128, B_), 512, 0, stream>>>(x, qkv_w, qkv_b, A);
  k_dw_reg<<<B_ * C3_, 256, 0, stream>>>(A, dw_w, dw_b, inv);
  k_attn_mfma<<<dim3(SPLITS_, HEAD_, B_), 256, 0, stream>>>(A, part);
  k_softmax<<<192, 256, 0, stream>>>(part, inv, attn_out);
  k_M<<<dim3(B_, HEAD_), 256, 0, stream>>>(attn_out, proj_w, Mbf);
  k7_mfma<<<dim3(N_ / 64, B_), 256, 0, stream>>>(A, Mbf, proj_b, out);
}

// Round 9
// 332.495 us; speedup vs baseline: 1.6598x; 1.0115x over previous
//
#include <hip/hip_runtime.h>
#include <hip/hip_bf16.h>

// Problem dims (StandardAttention): x[4,96,256,256], heads=3
#define B_  4
#define C_  96
#define H_  256
#define W_  256
#define N_  (H_*W_)      // 65536
#define C3_ 288
#define HEAD_ 3
#define HC_ 32
#define EPS_ 1e-12f
#define XP_ 104          // padded LDS row stride (ushorts): 52 words -> 2 lanes/bank (free)
#define SPLITS_ 128      // split-K segments for QK^T

typedef __attribute__((ext_vector_type(8))) short short8;
typedef __attribute__((ext_vector_type(4))) float f32x4;

// ---- bf16 helpers (raw ushort storage) -------------------------------------
__device__ __forceinline__ unsigned short f2bf(float f) {
  unsigned u = __float_as_uint(f);
  u += 0x7fffu + ((u >> 16) & 1u);      // round-to-nearest-even
  return (unsigned short)(u >> 16);
}
__device__ __forceinline__ float bf2f(unsigned short h) {
  return __uint_as_float((unsigned)h << 16);
}
__device__ __forceinline__ float bf_lo(unsigned u) { return __uint_as_float(u << 16); }
__device__ __forceinline__ float bf_hi(unsigned u) { return __uint_as_float(u & 0xffff0000u); }
__device__ __forceinline__ unsigned pack_bf(float a, float b) {
  return (unsigned)f2bf(a) | ((unsigned)f2bf(b) << 16);
}

// ---------------- K1: qkv = qkv_w @ x + qkv_b via MFMA ----------------------
// R1-proven form, FROZEN (85.6 us measured; every restructure since lost):
// 512 thr = 8 waves x 16 px; W staged once in LDS (padded rows, fp32->bf16
// on the fly); B-frags from global; scalar 2B stores; VGPR 52, acc in AGPRs.
__global__ __launch_bounds__(512) void k1_mfma(
    const float* __restrict__ x, const float* __restrict__ wsrc,
    const float* __restrict__ bias, unsigned short* __restrict__ out) {
  __shared__ unsigned short Wl[C3_ * XP_];    // 59904 B
  __shared__ float Bl[C3_];
  const int tid = threadIdx.x;
  const int b = blockIdx.y;
  for (int i = tid; i < C3_ * C_; i += 512)
    Wl[(i / 96) * XP_ + (i % 96)] = f2bf(wsrc[i]);
  for (int i = tid; i < C3_; i += 512) Bl[i] = bias[i];
  __syncthreads();
  const int lane = tid & 63;
  const int wv = tid >> 6;                    // 0..7
  const int l15 = lane & 15, quad = lane >> 4;
  const int gpix = blockIdx.x * 128 + wv * 16 + l15;
  const float* xcol = x + (size_t)b * C_ * N_ + gpix;
  short8 bfr[3];
#pragma unroll
  for (int kc = 0; kc < 3; ++kc) {
#pragma unroll
    for (int u = 0; u < 8; ++u)
      bfr[kc][u] = (short)f2bf(xcol[(size_t)(kc * 32 + quad * 8 + u) * N_]);
  }
  f32x4 acc[18];
#pragma unroll
  for (int m = 0; m < 18; ++m) acc[m] = (f32x4){0.f, 0.f, 0.f, 0.f};
#pragma unroll
  for (int m = 0; m < 18; ++m) {
#pragma unroll
    for (int kc = 0; kc < 3; ++kc) {
      const short8 afr = *reinterpret_cast<const short8*>(
          &Wl[(m * 16 + l15) * XP_ + kc * 32 + quad * 8]);
      acc[m] = __builtin_amdgcn_mfma_f32_16x16x32_bf16(afr, bfr[kc], acc[m], 0, 0, 0);
    }
  }
  unsigned short* ob = out + (size_t)b * C3_ * N_ + gpix;
#pragma unroll
  for (int m = 0; m < 18; ++m) {
    const int chb = m * 16 + quad * 4;
#pragma unroll
    for (int r = 0; r < 4; ++r)
      ob[(size_t)(chb + r) * N_] = f2bf(acc[m][r] + Bl[chb + r]);
  }
}

// ---------------- K2: 3x3 depthwise conv IN-PLACE, register-rolling ---------
// Raw-prefetch pipeline + halo via __shfl (proven R7/R8 form, frozen).
__global__ __launch_bounds__(256) void k_dw_reg(
    unsigned short* a, const float* __restrict__ w9,
    const float* __restrict__ bias, float* __restrict__ inv) {
  const int bc = blockIdx.x;            // 0..1151
  const int ch = bc % C3_;
  unsigned short* p = a + (size_t)bc * N_;
  const int tid = threadIdx.x;
  const int tr = tid >> 5;              // 0..7 row segment
  const int tc = tid & 31;
  const int x0 = tc * 8;
  const int y0 = tr * 32;
  float wv[9];
#pragma unroll
  for (int i = 0; i < 9; ++i) wv[i] = w9[ch * 9 + i];
  const float bv = bias[ch];

  auto load_raw = [&](int y) -> uint4 {
    if ((unsigned)y >= 256u) return make_uint4(0u, 0u, 0u, 0u);
    return *reinterpret_cast<const uint4*>(p + (size_t)y * W_ + x0);
  };
  auto finish = [&](const uint4& u, float* d) {
    d[1] = bf_lo(u.x); d[2] = bf_hi(u.x); d[3] = bf_lo(u.y); d[4] = bf_hi(u.y);
    d[5] = bf_lo(u.z); d[6] = bf_hi(u.z); d[7] = bf_lo(u.w); d[8] = bf_hi(u.w);
    // halo from neighbor lanes' registers (same 32-lane row group; boundary
    // lanes masked). lane tc-1's d[8] == x0-1, tc+1's d[1] == x0+8.
    const float left  = __shfl(d[8], (tid - 1) & 63, 64);
    const float right = __shfl(d[1], (tid + 1) & 63, 64);
    d[0] = (tc > 0)  ? left  : 0.f;
    d[9] = (tc < 31) ? right : 0.f;
  };

  float rm[10], rc[10], rn[10];
  finish(load_raw(y0 - 1), rm);
  finish(load_raw(y0), rc);
  uint4 rawn = load_raw(y0 + 1);        // row y0+1, finished at iter 0
  const uint4 rbr = load_raw(y0 + 32);  // bottom halo: ORIGINAL data, pre-barrier
  __syncthreads();                      // all preloads done before any write

  float ss = 0.f;
  for (int i = 0; i < 32; ++i) {
    const int y = y0 + i;
    // issue next raw load first (consumed next iteration) — wave-uniform select
    const uint4 rawnext = (i < 30) ? load_raw(y + 2) : rbr;
    finish(rawn, rn);                   // row y+1 (loaded last iteration)
    float o[8];
#pragma unroll
    for (int j = 0; j < 8; ++j) {
      o[j] = bv + wv[0] * rm[j] + wv[1] * rm[j + 1] + wv[2] * rm[j + 2]
                + wv[3] * rc[j] + wv[4] * rc[j + 1] + wv[5] * rc[j + 2]
                + wv[6] * rn[j] + wv[7] * rn[j + 1] + wv[8] * rn[j + 2];
      ss += o[j] * o[j];
    }
    uint4 st;
    st.x = pack_bf(o[0], o[1]); st.y = pack_bf(o[2], o[3]);
    st.z = pack_bf(o[4], o[5]); st.w = pack_bf(o[6], o[7]);
    *reinterpret_cast<uint4*>(p + (size_t)y * W_ + x0) = st;
#pragma unroll
    for (int j = 0; j < 10; ++j) { rm[j] = rc[j]; rc[j] = rn[j]; }
    rawn = rawnext;
  }
#pragma unroll
  for (int off = 32; off > 0; off >>= 1) ss += __shfl_down(ss, off, 64);
  __shared__ float red[4];
  if ((tid & 63) == 0) red[tid >> 6] = ss;
  __syncthreads();
  if (tid == 0 && ch < 192) {
    const float t = red[0] + red[1] + red[2] + red[3];
    const int b = bc / C3_;
    inv[b * 192 + ch] = 1.0f / fmaxf(sqrtf(t), EPS_);
  }
}

// ---------------- K4: QK^T via MFMA, split-K partials (no atomics) ----------
__global__ __launch_bounds__(256) void k_attn_mfma(
    const unsigned short* __restrict__ dw, float* __restrict__ part) {
  const int tid = threadIdx.x;
  const int lane = tid & 63;
  const int wv = tid >> 6;
  const int i0 = (wv >> 1) * 16, j0 = (wv & 1) * 16;
  const int h = blockIdx.y, b = blockIdx.z;
  const int n0 = blockIdx.x * (N_ / SPLITS_);    // 512-px segment
  const int l15 = lane & 15, quad = lane >> 4;
  const unsigned short* qrow =
      dw + ((size_t)(b * C3_ + h * HC_ + i0 + l15)) * N_ + n0 + quad * 8;
  const unsigned short* krow =
      dw + ((size_t)(b * C3_ + C_ + h * HC_ + j0 + l15)) * N_ + n0 + quad * 8;
  f32x4 acc = (f32x4){0.f, 0.f, 0.f, 0.f};
#pragma unroll 8
  for (int s = 0; s < N_ / SPLITS_; s += 32) {
    const short8 af = *reinterpret_cast<const short8*>(qrow + s);
    const short8 bf = *reinterpret_cast<const short8*>(krow + s);
    acc = __builtin_amdgcn_mfma_f32_16x16x32_bf16(af, bf, acc, 0, 0, 0);
  }
  float* pp = part + (size_t)blockIdx.x * (B_ * HEAD_ * 1024)
                   + ((size_t)(b * HEAD_ + h)) * 1024;
#pragma unroll
  for (int r = 0; r < 4; ++r)
    pp[(i0 + quad * 4 + r) * 32 + j0 + l15] = acc[r];
}

// ---------------- K5: reduce partials, scale by inv norms, softmax ----------
__global__ __launch_bounds__(256) void k_softmax(
    const float* __restrict__ part, const float* __restrict__ inv,
    float* __restrict__ attn_out) {
  __shared__ float red[2][4][32];
  const int tid = threadIdx.x;
  {
    const int r2 = tid >> 7;          // 0..1: row within block
    const int loc = tid & 127;
    const int sg = loc >> 5;          // 0..3: split group
    const int j = loc & 31;
    const int R = blockIdx.x * 2 + r2;
    float v = 0.f;
#pragma unroll 8
    for (int s = sg; s < SPLITS_; s += 4)
      v += part[(size_t)s * (B_ * HEAD_ * 1024) + R * 32 + j];
    red[r2][sg][j] = v;
  }
  __syncthreads();
  if (tid < 64) {
    const int r2 = tid >> 5, j = tid & 31;
    const int R = blockIdx.x * 2 + r2;
    const int b = R / 96, rem = R % 96;
    const int h = rem / 32, i = rem % 32;
    float v = red[r2][0][j] + red[r2][1][j] + red[r2][2][j] + red[r2][3][j];
    v *= inv[b * 192 + h * 32 + i] * inv[b * 192 + 96 + h * 32 + j];  // TEMP=1
    float m = v;
#pragma unroll
    for (int off = 16; off > 0; off >>= 1) m = fmaxf(m, __shfl_xor(m, off, 32));
    const float e = __expf(v - m);
    float s = e;
#pragma unroll
    for (int off = 16; off > 0; off >>= 1) s += __shfl_xor(s, off, 32);
    attn_out[R * 32 + j] = e / s;
  }
}

// ---------------- K6: M_b = proj_w o attn  (per-batch 96x96, bf16) ----------
__global__ __launch_bounds__(256) void k_M(
    const float* __restrict__ attn, const float* __restrict__ proj_w,
    unsigned short* __restrict__ Mbf) {
  const int b = blockIdx.x, h = blockIdx.y;
  const int tid = threadIdx.x;
  __shared__ float As[1024];          // attn[b,h][i][j]
  __shared__ float Pw[C_ * 32];       // proj_w[o][h*32+i]
  for (int l = tid; l < 1024; l += 256)
    As[l] = attn[((size_t)b * HEAD_ + h) * 1024 + l];
  for (int l = tid; l < C_ * 32; l += 256)
    Pw[l] = proj_w[(l >> 5) * C_ + h * 32 + (l & 31)];
  __syncthreads();
  for (int e = tid; e < C_ * 32; e += 256) {
    const int o = e >> 5, j = e & 31;
    float s = 0.f;
#pragma unroll
    for (int i = 0; i < 32; ++i) s += Pw[o * 32 + i] * As[i * 32 + j];
    Mbf[(size_t)b * C_ * C_ + o * C_ + h * 32 + j] = f2bf(s);
  }
}

// ---------------- K7: out = M_b @ v + proj_b via MFMA, LDS-transposed V -----
// NEW: V tile (96ch x 64px, 13 KB) staged via coalesced uint4 global loads
// (3/thread, was 24 scalar 2B loads at 128KB stride) and transposed into LDS
// [px][ch] (stride 104 ushorts -> 16B-aligned b128 frag reads). A-frag = v
// from LDS, B-frag = M^T (18KB, L1-hot). float4 stores unchanged.
__global__ __launch_bounds__(256) void k7_mfma(
    const unsigned short* __restrict__ A /* workspace base */,
    const unsigned short* __restrict__ Mbf,
    const float* __restrict__ bias, float* __restrict__ out) {
  __shared__ unsigned short Vt[64 * XP_];   // 13312 B, [local px][ch]
  const int tid = threadIdx.x;
  const int b = blockIdx.y;
  const int pixblk = blockIdx.x * 64;
  const unsigned short* vbase = A + ((size_t)(b * C3_ + 2 * C_)) * N_ + pixblk;
  // stage+transpose: 96 ch x 8 px-chunks = 768 uint4 chunks, 3 per thread
  for (int id = tid; id < 768; id += 256) {
    const int c = id >> 3, xc = id & 7;
    const uint4 u = *reinterpret_cast<const uint4*>(vbase + (size_t)c * N_ + xc * 8);
    const unsigned short* pu = reinterpret_cast<const unsigned short*>(&u);
#pragma unroll
    for (int j = 0; j < 8; ++j) Vt[(xc * 8 + j) * XP_ + c] = pu[j];
  }
  __syncthreads();
  const int lane = tid & 63;
  const int wv = tid >> 6;
  const int l15 = lane & 15, quad = lane >> 4;
  const int lpx = wv * 16 + l15;            // 0..63 local pixel
  const unsigned short* Mb = Mbf + (size_t)b * C_ * C_;
  short8 afr[3];
#pragma unroll
  for (int kc = 0; kc < 3; ++kc)
    afr[kc] = *reinterpret_cast<const short8*>(&Vt[lpx * XP_ + kc * 32 + quad * 8]);
  f32x4 acc[6];
#pragma unroll
  for (int m = 0; m < 6; ++m) acc[m] = (f32x4){0.f, 0.f, 0.f, 0.f};
#pragma unroll
  for (int m = 0; m < 6; ++m) {
#pragma unroll
    for (int kc = 0; kc < 3; ++kc) {
      // B-frag = M^T: k = in_ch quad*8+u, col = out_ch m*16+l15
      const short8 mfr = *reinterpret_cast<const short8*>(
          Mb + (m * 16 + l15) * C_ + kc * 32 + quad * 8);
      acc[m] = __builtin_amdgcn_mfma_f32_16x16x32_bf16(afr[kc], mfr, acc[m], 0, 0, 0);
    }
  }
  float* ob = out + (size_t)b * C_ * N_ + pixblk + wv * 16 + quad * 4;
#pragma unroll
  for (int m = 0; m < 6; ++m) {
    const float bv = bias[m * 16 + l15];
    f32x4 st;
#pragma unroll
    for (int r = 0; r < 4; ++r) st[r] = acc[m][r] + bv;
    *reinterpret_cast<f32x4*>(ob + (size_t)(m * 16 + l15) * N_) = st;
  }
}

extern "C" void kernel_launch(void* const* d_in, const int* in_sizes, int n_in,
                              void* d_out, int out_size, void* d_ws, size_t ws_size,
                              hipStream_t stream) {
  const float* x      = (const float*)d_in[0];
  const float* qkv_w  = (const float*)d_in[1];
  const float* qkv_b  = (const float*)d_in[2];
  const float* dw_w   = (const float*)d_in[3];
  const float* dw_b   = (const float*)d_in[4];
  const float* proj_w = (const float*)d_in[5];
  const float* proj_b = (const float*)d_in[6];

  float* out      = (float*)d_out;                       // [4,96,256,256]
  float* attn_out = out + (size_t)B_ * C_ * N_;          // [4,3,32,32]

  // Workspace: A 151MB | inv 3KB | part 6.3MB | Mbf 74KB
  unsigned short* A = (unsigned short*)d_ws;
  float* inv   = (float*)(A + (size_t)B_ * C3_ * N_);
  float* part  = inv + 768;
  unsigned short* Mbf = (unsigned short*)(part + (size_t)SPLITS_ * B_ * HEAD_ * 1024);

  k1_mfma<<<dim3(N_ / 128, B_), 512, 0, stream>>>(x, qkv_w, qkv_b, A);
  k_dw_reg<<<B_ * C3_, 256, 0, stream>>>(A, dw_w, dw_b, inv);
  k_attn_mfma<<<dim3(SPLITS_, HEAD_, B_), 256, 0, stream>>>(A, part);
  k_softmax<<<192, 256, 0, stream>>>(part, inv, attn_out);
  k_M<<<dim3(B_, HEAD_), 256, 0, stream>>>(attn_out, proj_w, Mbf);
  k7_mfma<<<dim3(N_ / 64, B_), 256, 0, stream>>>(A, Mbf, proj_b, out);
}